// Round 11
// baseline (291.750 us; speedup 1.0000x reference)
//
#include <hip/hip_runtime.h>
#include <math.h>

#define NN 10000
#define EE 320000

// d_out element offsets (f32), in reference return order
#define OQF  0LL
#define OQG  100000LL
#define OQD  200000LL
#define OADJ 300000LL
#define OZF  100300000LL
#define OMU  100940000LL
#define OLS  101580000LL
#define OL0  102220000LL
#define OZD  102220001LL
#define OWT  102860001LL
#define OREC 102880001LL

typedef short short8 __attribute__((ext_vector_type(8)));
typedef float f32x4 __attribute__((ext_vector_type(4)));

static __device__ __forceinline__ ushort f2bf(float f) {
  uint u = __float_as_uint(f);
  return (ushort)((u + 0x7fffu + ((u >> 16) & 1u)) >> 16);
}

// ------ prep: bucket scatter (indep) + x->bf16 + weight transposes -------------------
__global__ __launch_bounds__(256) void k_prep(
    const float* __restrict__ x,
    const int* __restrict__ row, const int* __restrict__ col,
    const float* __restrict__ avals,
    const float* __restrict__ gcnW, const float* __restrict__ nbW,
    const float* __restrict__ sfW, const float* __restrict__ d2W,
    const float* __restrict__ d1W, const float* __restrict__ m1W,
    const float* __restrict__ s1W, const float* __restrict__ m2W,
    const float* __restrict__ s2W,
    float2* __restrict__ BK8, int* __restrict__ cnt,
    ushort* __restrict__ XB,
    ushort* __restrict__ GWT, ushort* __restrict__ NWT, ushort* __restrict__ SWT,
    ushort* __restrict__ D2T, ushort* __restrict__ D1T, ushort* __restrict__ M1T,
    ushort* __restrict__ S1T, ushort* __restrict__ M2T, ushort* __restrict__ S2T)
{
  const int b = blockIdx.x, tid = threadIdx.x;
  if (b < 1250) {                       // bucket scatter: {col, aval} per edge
    const int e = b * 256 + tid;
    const int r = row[e];
    const int p = atomicAdd(&cnt[r], 1);
    if (p < 64) BK8[(size_t)r * 64 + p] = make_float2(__int_as_float(col[e]), avals[e]);
    return;
  }
  if (b < 3750) {                       // x -> bf16 (NN*256 = 2500*1024 exact)
    const int i = (b - 1250) * 1024 + tid * 4;
    const float4 v = *(const float4*)(x + i);
    ushort4 u;
    u.x = f2bf(v.x); u.y = f2bf(v.y); u.z = f2bf(v.z); u.w = f2bf(v.w);
    *(ushort4*)(XB + i) = u;
    return;
  }
  const int t2 = b - 3750;
  if (t2 < 1024) {                      // [256,256] -> [n][k]
    const int m = t2 >> 8, n = t2 & 255;
    const float* src = (m == 0) ? gcnW : (m == 1) ? nbW : (m == 2) ? sfW : d2W;
    ushort* dst = (m == 0) ? GWT : (m == 1) ? NWT : (m == 2) ? SWT : D2T;
    dst[n * 256 + tid] = f2bf(src[tid * 256 + n]);
  } else if (t2 < 1088) {               // d1W [64,256] -> D1T [256][64]
    const int local = (t2 - 1024) * 256 + tid;
    const int n = local >> 6, k = local & 63;
    D1T[local] = f2bf(d1W[k * 256 + n]);
  } else if (t2 < 1152) {               // m1W [256,64] -> M1T [64][256]
    const int n = t2 - 1088;
    M1T[n * 256 + tid] = f2bf(m1W[tid * 64 + n]);
  } else if (t2 < 1216) {               // s1W -> S1T
    const int n = t2 - 1152;
    S1T[n * 256 + tid] = f2bf(s1W[tid * 64 + n]);
  } else if (t2 < 1232) {               // m2W [64,64] -> M2T
    const int local = (t2 - 1216) * 256 + tid;
    const int n = local >> 6, k = local & 63;
    M2T[local] = f2bf(m2W[k * 64 + n]);
  } else {                              // s2W -> S2T
    const int local = (t2 - 1232) * 256 + tid;
    const int n = local >> 6, k = local & 63;
    S2T[local] = f2bf(s2W[k * 64 + n]);
  }
}

// ------ fused 3-way input GEMM via MFMA; A1/A2 via LDS cross-wave reduce (no atomics) -
__global__ __launch_bounds__(256) void k_gin(
    const ushort* __restrict__ XB,
    const ushort* __restrict__ GWT, const ushort* __restrict__ NWT,
    const ushort* __restrict__ SWT,
    const float* __restrict__ gcnb, const float* __restrict__ nbb,
    const float* __restrict__ sfb, const float* __restrict__ attW,
    ushort* __restrict__ xwb, float* __restrict__ a1, float* __restrict__ a2)
{
  __shared__ float sred[4][64];
  const int sel = blockIdx.y;
  const ushort* WT = (sel == 0) ? GWT : (sel == 1) ? NWT : SWT;
  const float* B = (sel == 0) ? gcnb : (sel == 1) ? nbb : sfb;
  const float* redw = attW + ((sel == 2) ? 256 : 0);
  float* redout = (sel == 1) ? a1 : a2;

  const int tid = threadIdx.x;
  const int wave = tid >> 6, lane = tid & 63;
  const int lr = lane & 15, lk = lane >> 4;
  const int i0 = blockIdx.x * 64;
  const int j0 = wave * 64;

  f32x4 acc[4][4];
#pragma unroll
  for (int ti = 0; ti < 4; ++ti)
#pragma unroll
    for (int tj = 0; tj < 4; ++tj) acc[ti][tj] = (f32x4){0.f, 0.f, 0.f, 0.f};

  const short8 z8 = {0, 0, 0, 0, 0, 0, 0, 0};
  for (int kk = 0; kk < 8; ++kk) {
    short8 a[4], bfr[4];
#pragma unroll
    for (int t = 0; t < 4; ++t) {
      const int ri = i0 + t * 16 + lr;
      a[t] = (ri < NN) ? *(const short8*)(XB + (size_t)ri * 256 + kk * 32 + lk * 8) : z8;
      bfr[t] = *(const short8*)(WT + (size_t)(j0 + t * 16 + lr) * 256 + kk * 32 + lk * 8);
    }
#pragma unroll
    for (int ti = 0; ti < 4; ++ti)
#pragma unroll
      for (int tj = 0; tj < 4; ++tj)
        acc[ti][tj] = __builtin_amdgcn_mfma_f32_16x16x32_bf16(a[ti], bfr[tj], acc[ti][tj], 0, 0, 0);
  }

  if (sel == 0) {
#pragma unroll
    for (int ti = 0; ti < 4; ++ti) {
      const int gi0 = i0 + ti * 16 + lk * 4;
#pragma unroll
      for (int tj = 0; tj < 4; ++tj) {
        const int gj = j0 + tj * 16 + lr;
        const float bv = B[gj];
#pragma unroll
        for (int r = 0; r < 4; ++r) {
          const int gi = gi0 + r;
          if (gi < NN) xwb[(size_t)gi * 256 + gj] = f2bf(acc[ti][tj][r] + bv);
        }
      }
    }
  } else {
    float bw[4], aw[4];
#pragma unroll
    for (int tj = 0; tj < 4; ++tj) {
      const int gj = j0 + tj * 16 + lr;
      bw[tj] = B[gj];
      aw[tj] = redw[gj];
    }
#pragma unroll
    for (int ti = 0; ti < 4; ++ti) {
#pragma unroll
      for (int r = 0; r < 4; ++r) {
        float s = 0.f;
#pragma unroll
        for (int tj = 0; tj < 4; ++tj)
          s += fmaxf(acc[ti][tj][r] + bw[tj], 0.f) * aw[tj];
#pragma unroll
        for (int m = 1; m < 16; m <<= 1) s += __shfl_xor(s, m, 64);
        if (lr == 0) sred[wave][ti * 16 + lk * 4 + r] = s;
      }
    }
    __syncthreads();
    if (tid < 64) {
      const int gi = i0 + tid;
      if (gi < NN)
        redout[gi] = sred[0][tid] + sred[1][tid] + sred[2][tid] + sred[3][tid];
    }
  }
}

// ------ dengate: wave-per-row gate + mv + dinv + l0 ----------------------------------
__global__ __launch_bounds__(256) void k_dengate(
    const float2* __restrict__ BK8, const int* __restrict__ cnt,
    const float* __restrict__ a1, const float* __restrict__ a2,
    const float* __restrict__ attb,
    float* __restrict__ mvb, float* __restrict__ dinv, float* __restrict__ l0acc)
{
  __shared__ float sw[4];
  const int tid = threadIdx.x;
  const int wave = tid >> 6, lane = tid & 63;
  const int r = blockIdx.x * 4 + wave;   // 2500*4 = 10000 exact
  const int m = min(cnt[r], 64);
  float part = 0.f, mv = 0.f;
  if (lane < m) {
    const float2 e = BK8[(size_t)r * 64 + lane];
    const int c = __float_as_int(e.x);
    const float w = a1[r] + a2[c] + attb[0];
    const float gate = 1.f / (1.f + expf(-w));
    const float mask = fminf(fmaxf(gate * 1.6f - 0.5f, 0.f), 1.f);
    mv = e.y * mask;
    mvb[(size_t)r * 64 + lane] = mv;
    part = 1.f / (1.f + expf(-(w + 0.78845736f)));
  }
  float s = mv;
#pragma unroll
  for (int off = 32; off > 0; off >>= 1) {
    s += __shfl_xor(s, off, 64);
    part += __shfl_xor(part, off, 64);
  }
  if (lane == 0) {
    dinv[r] = fminf(rsqrtf(s + 1e-10f), 10.f);
    sw[wave] = part;
  }
  __syncthreads();
  if (tid == 0) atomicAdd(l0acc, sw[0] + sw[1] + sw[2] + sw[3]);
}

// ------ dual spmm over bf16 XW, 8B bucket + mv, bf16 H out ---------------------------
__global__ __launch_bounds__(256) void k_spmm(
    const ushort* __restrict__ xwb, const float2* __restrict__ BK8,
    const float* __restrict__ mvb,
    const int* __restrict__ cnt, const float* __restrict__ dinv,
    ushort* __restrict__ h1, ushort* __restrict__ h2)
{
  const int tid = threadIdx.x;
  const int n = blockIdx.x * 2 + (tid >> 7);
  const int c = tid & 127;   // cols 2c, 2c+1
  const int m = min(cnt[n], 64);
  const float dr = dinv[n];
  const float2* b8 = BK8 + (size_t)n * 64;
  const float* mvp = mvb + (size_t)n * 64;
  float a10 = 0.f, a11 = 0.f, a20 = 0.f, a21 = 0.f;
  float b10 = 0.f, b11 = 0.f, b20 = 0.f, b21 = 0.f;
  int i = 0;
  for (; i + 2 <= m; i += 2) {
    const float2 e0 = b8[i], e1 = b8[i + 1];
    const float mv0 = mvp[i], mv1 = mvp[i + 1];
    const int c0 = __float_as_int(e0.x), c1 = __float_as_int(e1.x);
    const uint u0 = *(const uint*)(xwb + (size_t)c0 * 256 + 2 * c);
    const uint u1 = *(const uint*)(xwb + (size_t)c1 * 256 + 2 * c);
    const float d0 = dr * dinv[c0] * mv0;
    const float d1 = dr * dinv[c1] * mv1;
    const float v00 = __uint_as_float(u0 << 16), v01 = __uint_as_float(u0 & 0xffff0000u);
    const float v10 = __uint_as_float(u1 << 16), v11 = __uint_as_float(u1 & 0xffff0000u);
    a10 = fmaf(e0.y, v00, a10); a11 = fmaf(e0.y, v01, a11);
    a20 = fmaf(d0, v00, a20);   a21 = fmaf(d0, v01, a21);
    b10 = fmaf(e1.y, v10, b10); b11 = fmaf(e1.y, v11, b11);
    b20 = fmaf(d1, v10, b20);   b21 = fmaf(d1, v11, b21);
  }
  if (i < m) {
    const float2 e0 = b8[i];
    const float mv0 = mvp[i];
    const int c0 = __float_as_int(e0.x);
    const uint u0 = *(const uint*)(xwb + (size_t)c0 * 256 + 2 * c);
    const float d0 = dr * dinv[c0] * mv0;
    const float v00 = __uint_as_float(u0 << 16), v01 = __uint_as_float(u0 & 0xffff0000u);
    a10 = fmaf(e0.y, v00, a10); a11 = fmaf(e0.y, v01, a11);
    a20 = fmaf(d0, v00, a20);   a21 = fmaf(d0, v01, a21);
  }
  a10 += b10; a11 += b11; a20 += b20; a21 += b21;
  const uint p1 = (uint)f2bf(fmaxf(a10, 0.f)) | ((uint)f2bf(fmaxf(a11, 0.f)) << 16);
  const uint p2 = (uint)f2bf(fmaxf(a20, 0.f)) | ((uint)f2bf(fmaxf(a21, 0.f)) << 16);
  *(uint*)(h1 + (size_t)n * 256 + 2 * c) = p1;
  *(uint*)(h2 + (size_t)n * 256 + 2 * c) = p2;
}

// ------ MFMA two-stage encoder tails -------------------------------------------------
__global__ __launch_bounds__(128) void k_tail(
    const ushort* __restrict__ H1B, const ushort* __restrict__ H2B,
    const ushort* __restrict__ M1T, const ushort* __restrict__ S1T,
    const ushort* __restrict__ M2T, const ushort* __restrict__ S2T,
    const float* __restrict__ m1b, const float* __restrict__ m2b,
    const float* __restrict__ s1b, const float* __restrict__ s2b,
    float* __restrict__ out, float* __restrict__ zden,
    ushort* __restrict__ zbg, ushort* __restrict__ zbd)
{
  const int v = blockIdx.y;
  const ushort* A   = (v == 2) ? H2B : H1B;
  const ushort* W1T = (v == 1) ? S1T : M1T;
  const float*  B1  = (v == 1) ? s1b : m1b;
  const ushort* W2T = (v == 1) ? S2T : M2T;
  const float*  B2  = (v == 1) ? s2b : m2b;

  __shared__ ushort Ts[128][72];
  const int tid = threadIdx.x;
  const int wave = tid >> 6, lane = tid & 63;
  const int lr = lane & 15, lk = lane >> 4;
  const int i0 = blockIdx.x * 128 + wave * 64;
  const short8 z8 = {0, 0, 0, 0, 0, 0, 0, 0};

  f32x4 acc[4][4];
#pragma unroll
  for (int ti = 0; ti < 4; ++ti)
#pragma unroll
    for (int tj = 0; tj < 4; ++tj) acc[ti][tj] = (f32x4){0.f, 0.f, 0.f, 0.f};
  for (int kk = 0; kk < 8; ++kk) {
    short8 a[4], bfr[4];
#pragma unroll
    for (int t = 0; t < 4; ++t) {
      const int ri = i0 + t * 16 + lr;
      a[t] = (ri < NN) ? *(const short8*)(A + (size_t)ri * 256 + kk * 32 + lk * 8) : z8;
      bfr[t] = *(const short8*)(W1T + (size_t)(t * 16 + lr) * 256 + kk * 32 + lk * 8);
    }
#pragma unroll
    for (int ti = 0; ti < 4; ++ti)
#pragma unroll
      for (int tj = 0; tj < 4; ++tj)
        acc[ti][tj] = __builtin_amdgcn_mfma_f32_16x16x32_bf16(a[ti], bfr[tj], acc[ti][tj], 0, 0, 0);
  }
#pragma unroll
  for (int ti = 0; ti < 4; ++ti) {
#pragma unroll
    for (int tj = 0; tj < 4; ++tj) {
      const int cl = tj * 16 + lr;
      const float b1 = B1[cl];
#pragma unroll
      for (int r = 0; r < 4; ++r) {
        const int lrow = wave * 64 + ti * 16 + lk * 4 + r;
        Ts[lrow][cl] = f2bf(fmaxf(acc[ti][tj][r] + b1, 0.f));
      }
    }
  }
  __syncthreads();
  f32x4 acc2[4][4];
#pragma unroll
  for (int ti = 0; ti < 4; ++ti)
#pragma unroll
    for (int tj = 0; tj < 4; ++tj) acc2[ti][tj] = (f32x4){0.f, 0.f, 0.f, 0.f};
  for (int kk = 0; kk < 2; ++kk) {
    short8 a[4], bfr[4];
#pragma unroll
    for (int t = 0; t < 4; ++t) {
      a[t] = *(const short8*)(&Ts[wave * 64 + t * 16 + lr][kk * 32 + lk * 8]);
      bfr[t] = *(const short8*)(W2T + (size_t)(t * 16 + lr) * 64 + kk * 32 + lk * 8);
    }
#pragma unroll
    for (int ti = 0; ti < 4; ++ti)
#pragma unroll
      for (int tj = 0; tj < 4; ++tj)
        acc2[ti][tj] = __builtin_amdgcn_mfma_f32_16x16x32_bf16(a[ti], bfr[tj], acc2[ti][tj], 0, 0, 0);
  }
#pragma unroll
  for (int ti = 0; ti < 4; ++ti) {
    const int gi0 = i0 + ti * 16 + lk * 4;
#pragma unroll
    for (int tj = 0; tj < 4; ++tj) {
      const int gj = tj * 16 + lr;
      const float bv = B2[gj];
#pragma unroll
      for (int r = 0; r < 4; ++r) {
        const int gi = gi0 + r;
        if (gi >= NN) continue;
        float t = acc2[ti][tj][r] + bv;
        if (v == 0) {
          out[OMU + (size_t)gi * 64 + gj] = t;
          zbg[(size_t)gi * 64 + gj] = f2bf(t);
        } else if (v == 1) {
          t = (t > 20.f) ? t : log1pf(expf(t));
          out[OLS + (size_t)gi * 64 + gj] = t;
        } else {
          zden[(size_t)gi * 64 + gj] = t;
          out[OZD + (size_t)gi * 64 + gj] = t;
          zbd[(size_t)gi * 64 + gj] = f2bf(t);
        }
      }
    }
  }
}

// ------ fused post: recon (157) + mega (40) + zzt 128x128 tiles (6241) ---------------
// adj/rec writes are NON-TEMPORAL: pure streaming outputs, never re-read; bypass
// L2 write-allocate so the 400 MB stream doesn't thrash the 4 MB/XCD L2s.
__global__ __launch_bounds__(256) void k_post(
    const ushort* __restrict__ ZBG, const ushort* __restrict__ ZBD,
    const float* __restrict__ ZDENW,
    const ushort* __restrict__ D1T, const float* __restrict__ d1b,
    const ushort* __restrict__ D2T, const float* __restrict__ d2b,
    const float* __restrict__ f1W, const float* __restrict__ f1b,
    const float* __restrict__ f2W,
    const float* __restrict__ hW, const float* __restrict__ hb,
    const float* __restrict__ l0acc, float* __restrict__ out)
{
  __shared__ char smraw[64 * 264 * 2];   // recon HS (ushort) / zzt per-wave f32 stage
  const int b = blockIdx.x;
  const int tid = threadIdx.x;
  const short8 z8 = {0, 0, 0, 0, 0, 0, 0, 0};

  if (b < 157) {
    ushort* HS = (ushort*)smraw;
    const int wave = tid >> 6, lane = tid & 63;
    const int lr = lane & 15, lk = lane >> 4;
    const int i0 = b * 64;
    const int j0 = wave * 64;
    f32x4 acc[4][4];
#pragma unroll
    for (int ti = 0; ti < 4; ++ti)
#pragma unroll
      for (int tj = 0; tj < 4; ++tj) acc[ti][tj] = (f32x4){0.f, 0.f, 0.f, 0.f};
    for (int kk = 0; kk < 2; ++kk) {
      short8 a[4], bfr[4];
#pragma unroll
      for (int t = 0; t < 4; ++t) {
        const int ri = i0 + t * 16 + lr;
        a[t] = (ri < NN) ? *(const short8*)(ZBD + (size_t)ri * 64 + kk * 32 + lk * 8) : z8;
        bfr[t] = *(const short8*)(D1T + (size_t)(j0 + t * 16 + lr) * 64 + kk * 32 + lk * 8);
      }
#pragma unroll
      for (int ti = 0; ti < 4; ++ti)
#pragma unroll
        for (int tj = 0; tj < 4; ++tj)
          acc[ti][tj] = __builtin_amdgcn_mfma_f32_16x16x32_bf16(a[ti], bfr[tj], acc[ti][tj], 0, 0, 0);
    }
#pragma unroll
    for (int ti = 0; ti < 4; ++ti) {
      const int rl0 = ti * 16 + lk * 4;
#pragma unroll
      for (int tj = 0; tj < 4; ++tj) {
        const int cl = j0 + tj * 16 + lr;
        const float bv = d1b[cl];
#pragma unroll
        for (int r = 0; r < 4; ++r)
          HS[(rl0 + r) * 264 + cl] = f2bf(fmaxf(acc[ti][tj][r] + bv, 0.f));
      }
    }
    __syncthreads();
#pragma unroll
    for (int ti = 0; ti < 4; ++ti)
#pragma unroll
      for (int tj = 0; tj < 4; ++tj) acc[ti][tj] = (f32x4){0.f, 0.f, 0.f, 0.f};
    for (int kk = 0; kk < 8; ++kk) {
      short8 a[4], bfr[4];
#pragma unroll
      for (int t = 0; t < 4; ++t) {
        a[t] = *(const short8*)(HS + (t * 16 + lr) * 264 + kk * 32 + lk * 8);
        bfr[t] = *(const short8*)(D2T + (size_t)(j0 + t * 16 + lr) * 256 + kk * 32 + lk * 8);
      }
#pragma unroll
      for (int ti = 0; ti < 4; ++ti)
#pragma unroll
        for (int tj = 0; tj < 4; ++tj)
          acc[ti][tj] = __builtin_amdgcn_mfma_f32_16x16x32_bf16(a[ti], bfr[tj], acc[ti][tj], 0, 0, 0);
    }
#pragma unroll
    for (int ti = 0; ti < 4; ++ti) {
      const int gi0 = i0 + ti * 16 + lk * 4;
#pragma unroll
      for (int tj = 0; tj < 4; ++tj) {
        const int gj = j0 + tj * 16 + lr;
        const float bv = d2b[gj];
#pragma unroll
        for (int r = 0; r < 4; ++r) {
          const int gi = gi0 + r;
          if (gi < NN)
            __builtin_nontemporal_store(acc[ti][tj][r] + bv,
                                        out + OREC + (size_t)gi * 256 + gj);
        }
      }
    }
  } else if (b < 197) {
    const int n = (b - 157) * 256 + tid;
    if (n == 0) out[OL0] = l0acc[0] * (1.f / (float)EE);
    if (n >= NN) return;
    const float* zg = out + OMU + (size_t)n * 64;
    const float* zdn = ZDENW + (size_t)n * 64;
    float ag[32], ad[32];
#pragma unroll
    for (int c2 = 0; c2 < 32; ++c2) { const float bb = f1b[c2]; ag[c2] = bb; ad[c2] = bb; }
    for (int l = 0; l < 64; ++l) {
      const float a = zg[l];
      const float d = zdn[l];
#pragma unroll
      for (int c2 = 0; c2 < 32; ++c2) {
        const float w = f1W[l * 32 + c2];
        ag[c2] = fmaf(a, w, ag[c2]);
        ad[c2] = fmaf(d, w, ad[c2]);
      }
    }
    float sg = 0.f, sd = 0.f;
#pragma unroll
    for (int c2 = 0; c2 < 32; ++c2) {
      sg += tanhf(ag[c2]) * f2W[c2];
      sd += tanhf(ad[c2]) * f2W[c2];
    }
    const float e0 = sg * 2.f, e1 = sd * 2.f;
    const float m = fmaxf(e0, e1);
    float w0 = expf(e0 - m), w1 = expf(e1 - m);
    const float inv = 1.f / (w0 + w1);
    w0 *= inv; w1 *= inv;
    float lgf[10], lgg[10], lgd[10];
#pragma unroll
    for (int c = 0; c < 10; ++c) { const float bb = hb[c]; lgf[c] = bb; lgg[c] = bb; lgd[c] = bb; }
    for (int l = 0; l < 64; ++l) {
      const float zgv = zg[l], zdv = zdn[l];
      const float zfv = w0 * zgv + w1 * zdv;
      out[OZF + (size_t)n * 64 + l] = zfv;
#pragma unroll
      for (int c = 0; c < 10; ++c) {
        const float w = hW[l * 10 + c];
        lgf[c] = fmaf(zfv, w, lgf[c]);
        lgg[c] = fmaf(zgv, w, lgg[c]);
        lgd[c] = fmaf(zdv, w, lgd[c]);
      }
    }
#pragma unroll
    for (int h = 0; h < 3; ++h) {
      float* lg = (h == 0) ? lgf : (h == 1) ? lgg : lgd;
      float* q = out + ((h == 0) ? OQF : (h == 1) ? OQG : OQD) + (size_t)n * 10;
      float mm = lg[0];
#pragma unroll
      for (int c = 1; c < 10; ++c) mm = fmaxf(mm, lg[c]);
      float s = 0.f;
#pragma unroll
      for (int c = 0; c < 10; ++c) { lg[c] = expf(lg[c] - mm); s += lg[c]; }
      const float invq = 1.f / s;
#pragma unroll
      for (int c = 0; c < 10; ++c) q[c] = lg[c] * invq;
    }
    out[OWT + (size_t)n * 2 + 0] = w0;
    out[OWT + (size_t)n * 2 + 1] = w1;
  } else {
    // ---- zzt: 128x128 tiles, per-wave LDS stage, nontemporal dwordx4 stores ----
    const int bb = b - 197;
    const int bi = bb / 79, bj = bb % 79;
    const int wave = tid >> 6, lane = tid & 63;
    const int lr = lane & 15, lk = lane >> 4;
    const int i0 = bi * 128 + (wave >> 1) * 64;
    const int j0 = bj * 128 + (wave & 1) * 64;
    float* zs = (float*)smraw + wave * (16 * 76);  // per-wave private [16][76]
    short8 a[4][2], bfr[4][2];
#pragma unroll
    for (int t = 0; t < 4; ++t) {
      const int ri = i0 + t * 16 + lr;
      const int rj = j0 + t * 16 + lr;
#pragma unroll
      for (int kk = 0; kk < 2; ++kk) {
        a[t][kk] = (ri < NN) ? *(const short8*)(ZBG + (size_t)ri * 64 + kk * 32 + lk * 8) : z8;
        bfr[t][kk] = (rj < NN) ? *(const short8*)(ZBG + (size_t)rj * 64 + kk * 32 + lk * 8) : z8;
      }
    }
    f32x4 acc[4][4];
#pragma unroll
    for (int ti = 0; ti < 4; ++ti)
#pragma unroll
      for (int tj = 0; tj < 4; ++tj) {
        acc[ti][tj] = (f32x4){0.f, 0.f, 0.f, 0.f};
        acc[ti][tj] = __builtin_amdgcn_mfma_f32_16x16x32_bf16(a[ti][0], bfr[tj][0], acc[ti][tj], 0, 0, 0);
        acc[ti][tj] = __builtin_amdgcn_mfma_f32_16x16x32_bf16(a[ti][1], bfr[tj][1], acc[ti][tj], 0, 0, 0);
      }
#pragma unroll
    for (int ti = 0; ti < 4; ++ti) {
#pragma unroll
      for (int tj = 0; tj < 4; ++tj)
#pragma unroll
        for (int r = 0; r < 4; ++r)
          zs[(lk * 4 + r) * 76 + tj * 16 + lr] = acc[ti][tj][r];
#pragma unroll
      for (int s = 0; s < 4; ++s) {
        const int rrow = (s & 1) * 8 + (lane >> 3);
        const int ccol = (s >> 1) * 32 + (lane & 7) * 4;
        const int gi = i0 + ti * 16 + rrow;
        const int gj = j0 + ccol;
        if (gi < NN && gj < NN) {
          f32x4 v;
          v[0] = zs[rrow * 76 + ccol + 0];
          v[1] = zs[rrow * 76 + ccol + 1];
          v[2] = zs[rrow * 76 + ccol + 2];
          v[3] = zs[rrow * 76 + ccol + 3];
          __builtin_nontemporal_store(v, (f32x4*)(out + OADJ + (size_t)gi * NN + gj));
        }
      }
    }
  }
}

extern "C" void kernel_launch(void* const* d_in, const int* in_sizes, int n_in,
                              void* d_out, int out_size, void* d_ws, size_t ws_size,
                              hipStream_t stream)
{
  const float* x     = (const float*)d_in[0];
  const int*   row   = (const int*)d_in[1];
  const int*   col   = (const int*)d_in[2];
  const float* avals = (const float*)d_in[3];
  const float* gcnW  = (const float*)d_in[4];
  const float* gcnb  = (const float*)d_in[5];
  const float* m1W   = (const float*)d_in[6];
  const float* m1b   = (const float*)d_in[7];
  const float* m2W   = (const float*)d_in[8];
  const float* m2b   = (const float*)d_in[9];
  const float* s1W   = (const float*)d_in[10];
  const float* s1b   = (const float*)d_in[11];
  const float* s2W   = (const float*)d_in[12];
  const float* s2b   = (const float*)d_in[13];
  const float* nbW   = (const float*)d_in[14];
  const float* nbb   = (const float*)d_in[15];
  const float* sfW   = (const float*)d_in[16];
  const float* sfb   = (const float*)d_in[17];
  const float* attW  = (const float*)d_in[18];
  const float* attb  = (const float*)d_in[19];
  const float* f1W   = (const float*)d_in[20];
  const float* f1b   = (const float*)d_in[21];
  const float* f2W   = (const float*)d_in[22];
  const float* headW = (const float*)d_in[23];
  const float* headb = (const float*)d_in[24];
  const float* d1W   = (const float*)d_in[25];
  const float* d1b   = (const float*)d_in[26];
  const float* d2W   = (const float*)d_in[27];
  const float* d2b   = (const float*)d_in[28];
  float* out = (float*)d_out;

  float* ws = (float*)d_ws;
  size_t o = 0;
  float2* BK8  = (float2*)(ws + o); o += (size_t)NN * 64 * 2;  // {colbits, aval} 8B/edge
  float* MVB   = ws + o; o += (size_t)NN * 64;                 // masked val per slot
  ushort* XB   = (ushort*)(ws + o); o += (size_t)NN * 128;
  ushort* XWB  = (ushort*)(ws + o); o += (size_t)NN * 128;
  ushort* GWT  = (ushort*)(ws + o); o += 32768;
  ushort* NWT  = (ushort*)(ws + o); o += 32768;
  ushort* SWT  = (ushort*)(ws + o); o += 32768;
  ushort* D2T  = (ushort*)(ws + o); o += 32768;
  ushort* D1T  = (ushort*)(ws + o); o += 8192;
  ushort* M1T  = (ushort*)(ws + o); o += 8192;
  ushort* S1T  = (ushort*)(ws + o); o += 8192;
  ushort* M2T  = (ushort*)(ws + o); o += 2048;
  ushort* S2T  = (ushort*)(ws + o); o += 2048;
  ushort* H1B  = (ushort*)(ws + o); o += (size_t)NN * 128;
  ushort* H2B  = (ushort*)(ws + o); o += (size_t)NN * 128;
  float* ZDENW = ws + o; o += (size_t)NN * 64;
  ushort* ZBG  = (ushort*)(ws + o); o += (size_t)NN * 32;
  ushort* ZBD  = (ushort*)(ws + o); o += (size_t)NN * 32;
  float* DINV  = ws + o; o += NN;
  float* A1    = ws + o; o += NN;
  float* A2    = ws + o; o += NN;
  const size_t zoff = o;           // zero region: CNT + L0A
  int*   CNT   = (int*)(ws + o); o += NN;
  float* L0A   = ws + o; o += 1;

  hipMemsetAsync((void*)(ws + zoff), 0, (o - zoff) * sizeof(float), stream);

  k_prep<<<4998, 256, 0, stream>>>(x, row, col, avals,
                                   gcnW, nbW, sfW, d2W, d1W, m1W, s1W, m2W, s2W,
                                   BK8, CNT, XB,
                                   GWT, NWT, SWT, D2T, D1T, M1T, S1T, M2T, S2T);
  k_gin<<<dim3(157, 3), 256, 0, stream>>>(XB, GWT, NWT, SWT, gcnb, nbb, sfb, attW, XWB, A1, A2);
  k_dengate<<<2500, 256, 0, stream>>>(BK8, CNT, A1, A2, attb, MVB, DINV, L0A);
  k_spmm<<<NN / 2, 256, 0, stream>>>(XWB, BK8, MVB, CNT, DINV, H1B, H2B);
  k_tail<<<dim3(79, 3), 128, 0, stream>>>(H1B, H2B, M1T, S1T, M2T, S2T,
                                          m1b, m2b, s1b, s2b, out, ZDENW, ZBG, ZBD);
  k_post<<<6438, 256, 0, stream>>>(ZBG, ZBD, ZDENW, D1T, d1b, D2T, d2b,
                                   f1W, f1b, f2W, headW, headb, L0A, out);
}

// Round 12
// 283.059 us; speedup vs baseline: 1.0307x; 1.0307x over previous
//
#include <hip/hip_runtime.h>
#include <math.h>

#define NN 10000
#define EE 320000

// d_out element offsets (f32), in reference return order
#define OQF  0LL
#define OQG  100000LL
#define OQD  200000LL
#define OADJ 300000LL
#define OZF  100300000LL
#define OMU  100940000LL
#define OLS  101580000LL
#define OL0  102220000LL
#define OZD  102220001LL
#define OWT  102860001LL
#define OREC 102880001LL

typedef short short8 __attribute__((ext_vector_type(8)));
typedef float f32x4 __attribute__((ext_vector_type(4)));

static __device__ __forceinline__ ushort f2bf(float f) {
  uint u = __float_as_uint(f);
  return (ushort)((u + 0x7fffu + ((u >> 16) & 1u)) >> 16);
}

// ---------------- prep: x->bf16 + all weight transposes to [n][k] bf16 ---------------
__global__ __launch_bounds__(256) void k_prep(
    const float* __restrict__ x,
    const float* __restrict__ gcnW, const float* __restrict__ nbW,
    const float* __restrict__ sfW, const float* __restrict__ d2W,
    const float* __restrict__ d1W, const float* __restrict__ m1W,
    const float* __restrict__ s1W, const float* __restrict__ m2W,
    const float* __restrict__ s2W,
    ushort* __restrict__ XB,
    ushort* __restrict__ GWT, ushort* __restrict__ NWT, ushort* __restrict__ SWT,
    ushort* __restrict__ D2T, ushort* __restrict__ D1T, ushort* __restrict__ M1T,
    ushort* __restrict__ S1T, ushort* __restrict__ M2T, ushort* __restrict__ S2T)
{
  const int b = blockIdx.x, tid = threadIdx.x;
  if (b < 2500) {                       // x -> bf16 (NN*256 = 2500*1024 exact)
    const int i = b * 1024 + tid * 4;
    const float4 v = *(const float4*)(x + i);
    ushort4 u;
    u.x = f2bf(v.x); u.y = f2bf(v.y); u.z = f2bf(v.z); u.w = f2bf(v.w);
    *(ushort4*)(XB + i) = u;
    return;
  }
  const int t2 = b - 2500;
  if (t2 < 1024) {                      // [256,256] -> [n][k]
    const int m = t2 >> 8, n = t2 & 255;
    const float* src = (m == 0) ? gcnW : (m == 1) ? nbW : (m == 2) ? sfW : d2W;
    ushort* dst = (m == 0) ? GWT : (m == 1) ? NWT : (m == 2) ? SWT : D2T;
    dst[n * 256 + tid] = f2bf(src[tid * 256 + n]);
  } else if (t2 < 1088) {               // d1W [64,256] -> D1T [256][64]
    const int local = (t2 - 1024) * 256 + tid;
    const int n = local >> 6, k = local & 63;
    D1T[local] = f2bf(d1W[k * 256 + n]);
  } else if (t2 < 1152) {               // m1W [256,64] -> M1T [64][256]
    const int n = t2 - 1088;
    M1T[n * 256 + tid] = f2bf(m1W[tid * 64 + n]);
  } else if (t2 < 1216) {               // s1W -> S1T
    const int n = t2 - 1152;
    S1T[n * 256 + tid] = f2bf(s1W[tid * 64 + n]);
  } else if (t2 < 1232) {               // m2W [64,64] -> M2T
    const int local = (t2 - 1216) * 256 + tid;
    const int n = local >> 6, k = local & 63;
    M2T[local] = f2bf(m2W[k * 64 + n]);
  } else {                              // s2W -> S2T
    const int local = (t2 - 1232) * 256 + tid;
    const int n = local >> 6, k = local & 63;
    S2T[local] = f2bf(s2W[k * 64 + n]);
  }
}

// ---------------- fused 3-way input GEMM via MFMA over bf16 XB -----------------------
__global__ __launch_bounds__(256) void k_gin(
    const ushort* __restrict__ XB,
    const ushort* __restrict__ GWT, const ushort* __restrict__ NWT,
    const ushort* __restrict__ SWT,
    const float* __restrict__ gcnb, const float* __restrict__ nbb,
    const float* __restrict__ sfb, const float* __restrict__ attW,
    ushort* __restrict__ xwb, float* __restrict__ a1, float* __restrict__ a2)
{
  const int sel = blockIdx.y;
  const ushort* WT = (sel == 0) ? GWT : (sel == 1) ? NWT : SWT;
  const float* B = (sel == 0) ? gcnb : (sel == 1) ? nbb : sfb;
  const float* redw = attW + ((sel == 2) ? 256 : 0);
  float* redout = (sel == 1) ? a1 : a2;

  const int tid = threadIdx.x;
  const int wave = tid >> 6, lane = tid & 63;
  const int lr = lane & 15, lk = lane >> 4;
  const int i0 = blockIdx.x * 64;
  const int j0 = wave * 64;

  f32x4 acc[4][4];
#pragma unroll
  for (int ti = 0; ti < 4; ++ti)
#pragma unroll
    for (int tj = 0; tj < 4; ++tj) acc[ti][tj] = (f32x4){0.f, 0.f, 0.f, 0.f};

  const short8 z8 = {0, 0, 0, 0, 0, 0, 0, 0};
  for (int kk = 0; kk < 8; ++kk) {
    short8 a[4], bfr[4];
#pragma unroll
    for (int t = 0; t < 4; ++t) {
      const int ri = i0 + t * 16 + lr;
      a[t] = (ri < NN) ? *(const short8*)(XB + (size_t)ri * 256 + kk * 32 + lk * 8) : z8;
      bfr[t] = *(const short8*)(WT + (size_t)(j0 + t * 16 + lr) * 256 + kk * 32 + lk * 8);
    }
#pragma unroll
    for (int ti = 0; ti < 4; ++ti)
#pragma unroll
      for (int tj = 0; tj < 4; ++tj)
        acc[ti][tj] = __builtin_amdgcn_mfma_f32_16x16x32_bf16(a[ti], bfr[tj], acc[ti][tj], 0, 0, 0);
  }

  if (sel == 0) {
#pragma unroll
    for (int ti = 0; ti < 4; ++ti) {
      const int gi0 = i0 + ti * 16 + lk * 4;
#pragma unroll
      for (int tj = 0; tj < 4; ++tj) {
        const int gj = j0 + tj * 16 + lr;
        const float bv = B[gj];
#pragma unroll
        for (int r = 0; r < 4; ++r) {
          const int gi = gi0 + r;
          if (gi < NN) xwb[(size_t)gi * 256 + gj] = f2bf(acc[ti][tj][r] + bv);
        }
      }
    }
  } else {
    float bw[4], aw[4];
#pragma unroll
    for (int tj = 0; tj < 4; ++tj) {
      const int gj = j0 + tj * 16 + lr;
      bw[tj] = B[gj];
      aw[tj] = redw[gj];
    }
#pragma unroll
    for (int ti = 0; ti < 4; ++ti) {
      const int gi0 = i0 + ti * 16 + lk * 4;
#pragma unroll
      for (int r = 0; r < 4; ++r) {
        float s = 0.f;
#pragma unroll
        for (int tj = 0; tj < 4; ++tj)
          s += fmaxf(acc[ti][tj][r] + bw[tj], 0.f) * aw[tj];
#pragma unroll
        for (int m = 1; m < 16; m <<= 1) s += __shfl_xor(s, m, 64);
        const int gi = gi0 + r;
        if (lr == 0 && gi < NN) atomicAdd(&redout[gi], s);
      }
    }
  }
}

// ---------------- denoiser edge pass -> packed bucket table --------------------------
__global__ __launch_bounds__(256) void k_denoise(
    const int* __restrict__ row, const int* __restrict__ col,
    const float* __restrict__ vals, const float* __restrict__ a1,
    const float* __restrict__ a2, const float* __restrict__ attb,
    float4* __restrict__ bk, int* __restrict__ cnt, float* __restrict__ l0acc)
{
  const int e = blockIdx.x * 256 + threadIdx.x;
  const int r = row[e], c = col[e];
  const float w = a1[r] + a2[c] + attb[0];
  const float gate = 1.f / (1.f + expf(-w));
  const float mask = fminf(fmaxf(gate * 1.6f - 0.5f, 0.f), 1.f);
  const float m = vals[e] * mask;
  const int p = atomicAdd(&cnt[r], 1);
  if (p < 64) bk[(size_t)r * 64 + p] = make_float4(__int_as_float(c), vals[e], m, 0.f);
  float part = 1.f / (1.f + expf(-(w + 0.78845736f)));
#pragma unroll
  for (int off = 32; off > 0; off >>= 1) part += __shfl_down(part, off);
  __shared__ float sw[4];
  if ((threadIdx.x & 63) == 0) sw[threadIdx.x >> 6] = part;
  __syncthreads();
  if (threadIdx.x == 0) atomicAdd(l0acc, sw[0] + sw[1] + sw[2] + sw[3]);
}

// ---------------- dinv: wave-per-row bucket mv-sum -> clamped rsqrt ------------------
__global__ __launch_bounds__(256) void k_dinv(
    const float4* __restrict__ bk, const int* __restrict__ cnt,
    float* __restrict__ dinv)
{
  const int tid = threadIdx.x;
  const int r = blockIdx.x * 4 + (tid >> 6);
  const int lane = tid & 63;
  if (r >= NN) return;
  const int m = min(cnt[r], 64);
  float s = (lane < m) ? bk[(size_t)r * 64 + lane].z : 0.f;
#pragma unroll
  for (int off = 32; off > 0; off >>= 1) s += __shfl_xor(s, off, 64);
  if (lane == 0) dinv[r] = fminf(rsqrtf(s + 1e-10f), 10.f);
}

// ---------------- dual spmm over bf16 XW, bucket edges, bf16 H out -------------------
__global__ __launch_bounds__(256) void k_spmm(
    const ushort* __restrict__ xwb, const float4* __restrict__ bk,
    const int* __restrict__ cnt, const float* __restrict__ dinv,
    ushort* __restrict__ h1, ushort* __restrict__ h2)
{
  const int tid = threadIdx.x;
  const int n = blockIdx.x * 2 + (tid >> 7);
  const int c = tid & 127;   // cols 2c, 2c+1
  const int m = min(cnt[n], 64);
  const float dr = dinv[n];
  const float4* b = bk + (size_t)n * 64;
  float a10 = 0.f, a11 = 0.f, a20 = 0.f, a21 = 0.f;
  float b10 = 0.f, b11 = 0.f, b20 = 0.f, b21 = 0.f;
  int i = 0;
  for (; i + 2 <= m; i += 2) {
    const float4 e0 = b[i], e1 = b[i + 1];
    const int c0 = __float_as_int(e0.x), c1 = __float_as_int(e1.x);
    const uint u0 = *(const uint*)(xwb + (size_t)c0 * 256 + 2 * c);
    const uint u1 = *(const uint*)(xwb + (size_t)c1 * 256 + 2 * c);
    const float d0 = dr * dinv[c0] * e0.z;
    const float d1 = dr * dinv[c1] * e1.z;
    const float v00 = __uint_as_float(u0 << 16), v01 = __uint_as_float(u0 & 0xffff0000u);
    const float v10 = __uint_as_float(u1 << 16), v11 = __uint_as_float(u1 & 0xffff0000u);
    a10 = fmaf(e0.y, v00, a10); a11 = fmaf(e0.y, v01, a11);
    a20 = fmaf(d0, v00, a20);   a21 = fmaf(d0, v01, a21);
    b10 = fmaf(e1.y, v10, b10); b11 = fmaf(e1.y, v11, b11);
    b20 = fmaf(d1, v10, b20);   b21 = fmaf(d1, v11, b21);
  }
  if (i < m) {
    const float4 e0 = b[i];
    const int c0 = __float_as_int(e0.x);
    const uint u0 = *(const uint*)(xwb + (size_t)c0 * 256 + 2 * c);
    const float d0 = dr * dinv[c0] * e0.z;
    const float v00 = __uint_as_float(u0 << 16), v01 = __uint_as_float(u0 & 0xffff0000u);
    a10 = fmaf(e0.y, v00, a10); a11 = fmaf(e0.y, v01, a11);
    a20 = fmaf(d0, v00, a20);   a21 = fmaf(d0, v01, a21);
  }
  a10 += b10; a11 += b11; a20 += b20; a21 += b21;
  const uint p1 = (uint)f2bf(fmaxf(a10, 0.f)) | ((uint)f2bf(fmaxf(a11, 0.f)) << 16);
  const uint p2 = (uint)f2bf(fmaxf(a20, 0.f)) | ((uint)f2bf(fmaxf(a21, 0.f)) << 16);
  *(uint*)(h1 + (size_t)n * 256 + 2 * c) = p1;
  *(uint*)(h2 + (size_t)n * 256 + 2 * c) = p2;
}

// ---------------- MFMA two-stage encoder tails ---------------------------------------
__global__ __launch_bounds__(128) void k_tail(
    const ushort* __restrict__ H1B, const ushort* __restrict__ H2B,
    const ushort* __restrict__ M1T, const ushort* __restrict__ S1T,
    const ushort* __restrict__ M2T, const ushort* __restrict__ S2T,
    const float* __restrict__ m1b, const float* __restrict__ m2b,
    const float* __restrict__ s1b, const float* __restrict__ s2b,
    float* __restrict__ out, float* __restrict__ zden,
    ushort* __restrict__ zbg, ushort* __restrict__ zbd)
{
  const int v = blockIdx.y;
  const ushort* A   = (v == 2) ? H2B : H1B;
  const ushort* W1T = (v == 1) ? S1T : M1T;
  const float*  B1  = (v == 1) ? s1b : m1b;
  const ushort* W2T = (v == 1) ? S2T : M2T;
  const float*  B2  = (v == 1) ? s2b : m2b;

  __shared__ ushort Ts[128][72];
  const int tid = threadIdx.x;
  const int wave = tid >> 6, lane = tid & 63;
  const int lr = lane & 15, lk = lane >> 4;
  const int i0 = blockIdx.x * 128 + wave * 64;
  const short8 z8 = {0, 0, 0, 0, 0, 0, 0, 0};

  f32x4 acc[4][4];
#pragma unroll
  for (int ti = 0; ti < 4; ++ti)
#pragma unroll
    for (int tj = 0; tj < 4; ++tj) acc[ti][tj] = (f32x4){0.f, 0.f, 0.f, 0.f};
  for (int kk = 0; kk < 8; ++kk) {
    short8 a[4], bfr[4];
#pragma unroll
    for (int t = 0; t < 4; ++t) {
      const int ri = i0 + t * 16 + lr;
      a[t] = (ri < NN) ? *(const short8*)(A + (size_t)ri * 256 + kk * 32 + lk * 8) : z8;
      bfr[t] = *(const short8*)(W1T + (size_t)(t * 16 + lr) * 256 + kk * 32 + lk * 8);
    }
#pragma unroll
    for (int ti = 0; ti < 4; ++ti)
#pragma unroll
      for (int tj = 0; tj < 4; ++tj)
        acc[ti][tj] = __builtin_amdgcn_mfma_f32_16x16x32_bf16(a[ti], bfr[tj], acc[ti][tj], 0, 0, 0);
  }
#pragma unroll
  for (int ti = 0; ti < 4; ++ti) {
#pragma unroll
    for (int tj = 0; tj < 4; ++tj) {
      const int cl = tj * 16 + lr;
      const float b1 = B1[cl];
#pragma unroll
      for (int r = 0; r < 4; ++r) {
        const int lrow = wave * 64 + ti * 16 + lk * 4 + r;
        Ts[lrow][cl] = f2bf(fmaxf(acc[ti][tj][r] + b1, 0.f));
      }
    }
  }
  __syncthreads();
  f32x4 acc2[4][4];
#pragma unroll
  for (int ti = 0; ti < 4; ++ti)
#pragma unroll
    for (int tj = 0; tj < 4; ++tj) acc2[ti][tj] = (f32x4){0.f, 0.f, 0.f, 0.f};
  for (int kk = 0; kk < 2; ++kk) {
    short8 a[4], bfr[4];
#pragma unroll
    for (int t = 0; t < 4; ++t) {
      a[t] = *(const short8*)(&Ts[wave * 64 + t * 16 + lr][kk * 32 + lk * 8]);
      bfr[t] = *(const short8*)(W2T + (size_t)(t * 16 + lr) * 64 + kk * 32 + lk * 8);
    }
#pragma unroll
    for (int ti = 0; ti < 4; ++ti)
#pragma unroll
      for (int tj = 0; tj < 4; ++tj)
        acc2[ti][tj] = __builtin_amdgcn_mfma_f32_16x16x32_bf16(a[ti], bfr[tj], acc2[ti][tj], 0, 0, 0);
  }
#pragma unroll
  for (int ti = 0; ti < 4; ++ti) {
    const int gi0 = i0 + ti * 16 + lk * 4;
#pragma unroll
    for (int tj = 0; tj < 4; ++tj) {
      const int gj = tj * 16 + lr;
      const float bv = B2[gj];
#pragma unroll
      for (int r = 0; r < 4; ++r) {
        const int gi = gi0 + r;
        if (gi >= NN) continue;
        float t = acc2[ti][tj][r] + bv;
        if (v == 0) {
          out[OMU + (size_t)gi * 64 + gj] = t;
          zbg[(size_t)gi * 64 + gj] = f2bf(t);
        } else if (v == 1) {
          t = (t > 20.f) ? t : log1pf(expf(t));
          out[OLS + (size_t)gi * 64 + gj] = t;
        } else {
          zden[(size_t)gi * 64 + gj] = t;
          out[OZD + (size_t)gi * 64 + gj] = t;
          zbd[(size_t)gi * 64 + gj] = f2bf(t);
        }
      }
    }
  }
}

// ---------------- fused post: recon (157) + mega (40) + zzt (6241) -------------------
__global__ __launch_bounds__(256) void k_post(
    const ushort* __restrict__ ZBG, const ushort* __restrict__ ZBD,
    const float* __restrict__ ZDENW,
    const ushort* __restrict__ D1T, const float* __restrict__ d1b,
    const ushort* __restrict__ D2T, const float* __restrict__ d2b,
    const float* __restrict__ f1W, const float* __restrict__ f1b,
    const float* __restrict__ f2W,
    const float* __restrict__ hW, const float* __restrict__ hb,
    const float* __restrict__ l0acc, float* __restrict__ out)
{
  __shared__ char smraw[64 * 264 * 2];   // recon: 33.8 KB ushort; zzt: 19.5 KB f32 stage
  const int b = blockIdx.x;
  const int tid = threadIdx.x;
  const short8 z8 = {0, 0, 0, 0, 0, 0, 0, 0};

  if (b < 157) {
    ushort* HS = (ushort*)smraw;
    const int wave = tid >> 6, lane = tid & 63;
    const int lr = lane & 15, lk = lane >> 4;
    const int i0 = b * 64;
    const int j0 = wave * 64;
    f32x4 acc[4][4];
#pragma unroll
    for (int ti = 0; ti < 4; ++ti)
#pragma unroll
      for (int tj = 0; tj < 4; ++tj) acc[ti][tj] = (f32x4){0.f, 0.f, 0.f, 0.f};
    for (int kk = 0; kk < 2; ++kk) {
      short8 a[4], bfr[4];
#pragma unroll
      for (int t = 0; t < 4; ++t) {
        const int ri = i0 + t * 16 + lr;
        a[t] = (ri < NN) ? *(const short8*)(ZBD + (size_t)ri * 64 + kk * 32 + lk * 8) : z8;
        bfr[t] = *(const short8*)(D1T + (size_t)(j0 + t * 16 + lr) * 64 + kk * 32 + lk * 8);
      }
#pragma unroll
      for (int ti = 0; ti < 4; ++ti)
#pragma unroll
        for (int tj = 0; tj < 4; ++tj)
          acc[ti][tj] = __builtin_amdgcn_mfma_f32_16x16x32_bf16(a[ti], bfr[tj], acc[ti][tj], 0, 0, 0);
    }
#pragma unroll
    for (int ti = 0; ti < 4; ++ti) {
      const int rl0 = ti * 16 + lk * 4;
#pragma unroll
      for (int tj = 0; tj < 4; ++tj) {
        const int cl = j0 + tj * 16 + lr;
        const float bv = d1b[cl];
#pragma unroll
        for (int r = 0; r < 4; ++r)
          HS[(rl0 + r) * 264 + cl] = f2bf(fmaxf(acc[ti][tj][r] + bv, 0.f));
      }
    }
    __syncthreads();
#pragma unroll
    for (int ti = 0; ti < 4; ++ti)
#pragma unroll
      for (int tj = 0; tj < 4; ++tj) acc[ti][tj] = (f32x4){0.f, 0.f, 0.f, 0.f};
    for (int kk = 0; kk < 8; ++kk) {
      short8 a[4], bfr[4];
#pragma unroll
      for (int t = 0; t < 4; ++t) {
        a[t] = *(const short8*)(HS + (t * 16 + lr) * 264 + kk * 32 + lk * 8);
        bfr[t] = *(const short8*)(D2T + (size_t)(j0 + t * 16 + lr) * 256 + kk * 32 + lk * 8);
      }
#pragma unroll
      for (int ti = 0; ti < 4; ++ti)
#pragma unroll
        for (int tj = 0; tj < 4; ++tj)
          acc[ti][tj] = __builtin_amdgcn_mfma_f32_16x16x32_bf16(a[ti], bfr[tj], acc[ti][tj], 0, 0, 0);
    }
#pragma unroll
    for (int ti = 0; ti < 4; ++ti) {
      const int gi0 = i0 + ti * 16 + lk * 4;
#pragma unroll
      for (int tj = 0; tj < 4; ++tj) {
        const int gj = j0 + tj * 16 + lr;
        const float bv = d2b[gj];
#pragma unroll
        for (int r = 0; r < 4; ++r) {
          const int gi = gi0 + r;
          if (gi < NN) out[OREC + (size_t)gi * 256 + gj] = acc[ti][tj][r] + bv;
        }
      }
    }
  } else if (b < 197) {
    const int n = (b - 157) * 256 + tid;
    if (n == 0) out[OL0] = l0acc[0] * (1.f / (float)EE);
    if (n >= NN) return;
    const float* zg = out + OMU + (size_t)n * 64;
    const float* zdn = ZDENW + (size_t)n * 64;
    float ag[32], ad[32];
#pragma unroll
    for (int c2 = 0; c2 < 32; ++c2) { const float bb = f1b[c2]; ag[c2] = bb; ad[c2] = bb; }
    for (int l = 0; l < 64; ++l) {
      const float a = zg[l];
      const float d = zdn[l];
#pragma unroll
      for (int c2 = 0; c2 < 32; ++c2) {
        const float w = f1W[l * 32 + c2];
        ag[c2] = fmaf(a, w, ag[c2]);
        ad[c2] = fmaf(d, w, ad[c2]);
      }
    }
    float sg = 0.f, sd = 0.f;
#pragma unroll
    for (int c2 = 0; c2 < 32; ++c2) {
      sg += tanhf(ag[c2]) * f2W[c2];
      sd += tanhf(ad[c2]) * f2W[c2];
    }
    const float e0 = sg * 2.f, e1 = sd * 2.f;
    const float m = fmaxf(e0, e1);
    float w0 = expf(e0 - m), w1 = expf(e1 - m);
    const float inv = 1.f / (w0 + w1);
    w0 *= inv; w1 *= inv;
    float lgf[10], lgg[10], lgd[10];
#pragma unroll
    for (int c = 0; c < 10; ++c) { const float bb = hb[c]; lgf[c] = bb; lgg[c] = bb; lgd[c] = bb; }
    for (int l = 0; l < 64; ++l) {
      const float zgv = zg[l], zdv = zdn[l];
      const float zfv = w0 * zgv + w1 * zdv;
      out[OZF + (size_t)n * 64 + l] = zfv;
#pragma unroll
      for (int c = 0; c < 10; ++c) {
        const float w = hW[l * 10 + c];
        lgf[c] = fmaf(zfv, w, lgf[c]);
        lgg[c] = fmaf(zgv, w, lgg[c]);
        lgd[c] = fmaf(zdv, w, lgd[c]);
      }
    }
#pragma unroll
    for (int h = 0; h < 3; ++h) {
      float* lg = (h == 0) ? lgf : (h == 1) ? lgg : lgd;
      float* q = out + ((h == 0) ? OQF : (h == 1) ? OQG : OQD) + (size_t)n * 10;
      float mm = lg[0];
#pragma unroll
      for (int c = 1; c < 10; ++c) mm = fmaxf(mm, lg[c]);
      float s = 0.f;
#pragma unroll
      for (int c = 0; c < 10; ++c) { lg[c] = expf(lg[c] - mm); s += lg[c]; }
      const float invq = 1.f / s;
#pragma unroll
      for (int c = 0; c < 10; ++c) q[c] = lg[c] * invq;
    }
    out[OWT + (size_t)n * 2 + 0] = w0;
    out[OWT + (size_t)n * 2 + 1] = w1;
  } else {
    // ---- zzt with LDS-staged coalesced epilogue ----
    const int bb = b - 197;
    const int bi = bb / 79, bj = bb % 79;
    const int wave = tid >> 6, lane = tid & 63;
    const int lr = lane & 15, lk = lane >> 4;
    const int i0 = bi * 128 + (wave >> 1) * 64;
    const int j0 = bj * 128 + (wave & 1) * 64;
    float* zs = (float*)smraw + wave * (16 * 76);  // per-wave private [16][76] f32
    short8 a[4][2], bfr[4][2];
#pragma unroll
    for (int t = 0; t < 4; ++t) {
      const int ri = i0 + t * 16 + lr;
      const int rj = j0 + t * 16 + lr;
#pragma unroll
      for (int kk = 0; kk < 2; ++kk) {
        a[t][kk] = (ri < NN) ? *(const short8*)(ZBG + (size_t)ri * 64 + kk * 32 + lk * 8) : z8;
        bfr[t][kk] = (rj < NN) ? *(const short8*)(ZBG + (size_t)rj * 64 + kk * 32 + lk * 8) : z8;
      }
    }
    f32x4 acc[4][4];
#pragma unroll
    for (int ti = 0; ti < 4; ++ti)
#pragma unroll
      for (int tj = 0; tj < 4; ++tj) {
        acc[ti][tj] = (f32x4){0.f, 0.f, 0.f, 0.f};
        acc[ti][tj] = __builtin_amdgcn_mfma_f32_16x16x32_bf16(a[ti][0], bfr[tj][0], acc[ti][tj], 0, 0, 0);
        acc[ti][tj] = __builtin_amdgcn_mfma_f32_16x16x32_bf16(a[ti][1], bfr[tj][1], acc[ti][tj], 0, 0, 0);
      }
    // epilogue: per ti, stage 16x64 f32 in LDS, then 4x dwordx4 stores (8 rows x 128B)
#pragma unroll
    for (int ti = 0; ti < 4; ++ti) {
#pragma unroll
      for (int tj = 0; tj < 4; ++tj)
#pragma unroll
        for (int r = 0; r < 4; ++r)
          zs[(lk * 4 + r) * 76 + tj * 16 + lr] = acc[ti][tj][r];
#pragma unroll
      for (int s = 0; s < 4; ++s) {
        const int rrow = (s & 1) * 8 + (lane >> 3);
        const int ccol = (s >> 1) * 32 + (lane & 7) * 4;
        const int gi = i0 + ti * 16 + rrow;
        const int gj = j0 + ccol;
        if (gi < NN && gj < NN) {
          float4 v;
          v.x = zs[rrow * 76 + ccol + 0];
          v.y = zs[rrow * 76 + ccol + 1];
          v.z = zs[rrow * 76 + ccol + 2];
          v.w = zs[rrow * 76 + ccol + 3];
          *(float4*)(out + OADJ + (size_t)gi * NN + gj) = v;
        }
      }
    }
  }
}

extern "C" void kernel_launch(void* const* d_in, const int* in_sizes, int n_in,
                              void* d_out, int out_size, void* d_ws, size_t ws_size,
                              hipStream_t stream)
{
  const float* x     = (const float*)d_in[0];
  const int*   row   = (const int*)d_in[1];
  const int*   col   = (const int*)d_in[2];
  const float* avals = (const float*)d_in[3];
  const float* gcnW  = (const float*)d_in[4];
  const float* gcnb  = (const float*)d_in[5];
  const float* m1W   = (const float*)d_in[6];
  const float* m1b   = (const float*)d_in[7];
  const float* m2W   = (const float*)d_in[8];
  const float* m2b   = (const float*)d_in[9];
  const float* s1W   = (const float*)d_in[10];
  const float* s1b   = (const float*)d_in[11];
  const float* s2W   = (const float*)d_in[12];
  const float* s2b   = (const float*)d_in[13];
  const float* nbW   = (const float*)d_in[14];
  const float* nbb   = (const float*)d_in[15];
  const float* sfW   = (const float*)d_in[16];
  const float* sfb   = (const float*)d_in[17];
  const float* attW  = (const float*)d_in[18];
  const float* attb  = (const float*)d_in[19];
  const float* f1W   = (const float*)d_in[20];
  const float* f1b   = (const float*)d_in[21];
  const float* f2W   = (const float*)d_in[22];
  const float* headW = (const float*)d_in[23];
  const float* headb = (const float*)d_in[24];
  const float* d1W   = (const float*)d_in[25];
  const float* d1b   = (const float*)d_in[26];
  const float* d2W   = (const float*)d_in[27];
  const float* d2b   = (const float*)d_in[28];
  float* out = (float*)d_out;

  float* ws = (float*)d_ws;
  size_t o = 0;
  float4* BK   = (float4*)(ws + o); o += (size_t)NN * 64 * 4;  // bucket table [NN][64] f4
  ushort* XB   = (ushort*)(ws + o); o += (size_t)NN * 128;     // bf16 x [NN,256]
  ushort* XWB  = (ushort*)(ws + o); o += (size_t)NN * 128;     // bf16 [NN,256]
  ushort* GWT  = (ushort*)(ws + o); o += 32768;                // bf16 [256][256] (W^T)
  ushort* NWT  = (ushort*)(ws + o); o += 32768;
  ushort* SWT  = (ushort*)(ws + o); o += 32768;
  ushort* D2T  = (ushort*)(ws + o); o += 32768;
  ushort* D1T  = (ushort*)(ws + o); o += 8192;                 // bf16 [256][64]
  ushort* M1T  = (ushort*)(ws + o); o += 8192;                 // bf16 [64][256]
  ushort* S1T  = (ushort*)(ws + o); o += 8192;
  ushort* M2T  = (ushort*)(ws + o); o += 2048;                 // bf16 [64][64]
  ushort* S2T  = (ushort*)(ws + o); o += 2048;
  ushort* H1B  = (ushort*)(ws + o); o += (size_t)NN * 128;     // bf16 [NN,256]
  ushort* H2B  = (ushort*)(ws + o); o += (size_t)NN * 128;
  float* ZDENW = ws + o; o += (size_t)NN * 64;
  ushort* ZBG  = (ushort*)(ws + o); o += (size_t)NN * 32;      // bf16 z_gen [NN,64]
  ushort* ZBD  = (ushort*)(ws + o); o += (size_t)NN * 32;      // bf16 z_den [NN,64]
  float* DINV  = ws + o; o += NN;
  const size_t zoff = o;
  float* A1    = ws + o; o += NN;
  float* A2    = ws + o; o += NN;
  int*   CNT   = (int*)(ws + o); o += NN;
  float* L0A   = ws + o; o += 1;

  hipMemsetAsync((void*)(ws + zoff), 0, (o - zoff) * sizeof(float), stream);

  k_prep<<<3748, 256, 0, stream>>>(x, gcnW, nbW, sfW, d2W, d1W, m1W, s1W, m2W, s2W,
                                   XB, GWT, NWT, SWT, D2T, D1T, M1T, S1T, M2T, S2T);
  k_gin<<<dim3(157, 3), 256, 0, stream>>>(XB, GWT, NWT, SWT, gcnb, nbb, sfb, attW, XWB, A1, A2);
  k_denoise<<<EE / 256, 256, 0, stream>>>(row, col, avals, A1, A2, attb, BK, CNT, L0A);
  k_dinv<<<2500, 256, 0, stream>>>(BK, CNT, DINV);
  k_spmm<<<NN / 2, 256, 0, stream>>>(XWB, BK, CNT, DINV, H1B, H2B);
  k_tail<<<dim3(79, 3), 128, 0, stream>>>(H1B, H2B, M1T, S1T, M2T, S2T,
                                          m1b, m2b, s1b, s2b, out, ZDENW, ZBG, ZBD);
  k_post<<<6438, 256, 0, stream>>>(ZBG, ZBD, ZDENW, D1T, d1b, D2T, d2b,
                                   f1W, f1b, f2W, headW, headb, L0A, out);
}